// Round 18
// baseline (245.786 us; speedup 1.0000x reference)
//
#include <hip/hip_runtime.h>
#include <cstdint>
#include <cstddef>

#define CCH 128
#define TK 4096      // edges per tile: nT=391 edge-tile blocks fused into lstm launch; 16 edges/thread
#define FCAP 5120    // fine-sort bucket capacity == fixed slot size (bucket ~4096+-64, 16-sigma headroom)
#define SLOT 5120    // fixed packed-array slot per coarse bucket
#define MAXBKT 512   // max coarse buckets (392 actual)
#define XPAD 136     // 128 + 8 bf16 pad
#define APAD 264     // 256 + 8 pad

typedef __attribute__((ext_vector_type(8))) short short8;
typedef __attribute__((ext_vector_type(4))) float floatx4;

__device__ __forceinline__ unsigned short f2bf(float f) {
    unsigned u = __builtin_bit_cast(unsigned, f);
    u += 0x7fffu + ((u >> 16) & 1u);   // RNE
    return (unsigned short)(u >> 16);
}
__device__ __forceinline__ float bf2f(unsigned short h) {
    unsigned u = ((unsigned)h) << 16;
    return __builtin_bit_cast(float, u);
}
__device__ __forceinline__ float sigmoidf_(float x) { return 1.0f / (1.0f + __expf(-x)); }
__device__ __forceinline__ float tanh_fast(float x) {
    x = fminf(fmaxf(x, -10.0f), 10.0f);
    float e = __expf(2.0f * x);
    return (e - 1.0f) / (e + 1.0f);
}

// ---------------- merged weight prep + btot zeroing ----------------
__global__ __launch_bounds__(256) void prep_weights_kernel(
    const float* __restrict__ Wih0, const float* __restrict__ Wih1,
    const float* __restrict__ Wlin0, const float* __restrict__ Wlin1,
    unsigned short* __restrict__ frag_ih, unsigned short* __restrict__ frag_lin,
    int* __restrict__ btot, int NBKT)
{
    int t = blockIdx.x * 256 + threadIdx.x;
    if (t < 12288) {
        int l  = t & 63;
        int kc = (t >> 6) & 3;
        int ct = (t >> 8) & 7;
        int g  = (t >> 11) % 3;
        int rel = t / 6144;
        int gb = (g == 0) ? 0 : (g == 1 ? 256 : 384);
        const float* W = rel ? Wih1 : Wih0;
        int n  = gb + ct * 16 + (l & 15);
        int kb = kc * 32 + (l >> 4) * 8;
        unsigned short* o = frag_ih + (size_t)t * 8;
#pragma unroll
        for (int j = 0; j < 8; j++) o[j] = f2bf(W[(size_t)n * CCH + kb + j]);
    } else if (t < 20480) {
        int t2 = t - 12288;
        int l  = t2 & 63;
        int kc = (t2 >> 6) & 7;
        int ct = (t2 >> 9) & 7;
        int rel = t2 >> 12;
        const float* W = rel ? Wlin1 : Wlin0;
        int n  = ct * 16 + (l & 15);
        int kb = kc * 32 + (l >> 4) * 8;
        unsigned short* o = frag_lin + (size_t)t2 * 8;
#pragma unroll
        for (int j = 0; j < 8; j++) o[j] = f2bf(W[(size_t)n * 256 + kb + j]);
    } else {
        int z = t - 20480;
        if (z < NBKT) btot[z] = 0;
    }
}

// ---------------- fused: LSTM GEMM (M=32) + full CSR scatter tiles ----------------
// blocks [0,nT): histogram + atomic range reservation + scatter (latency-bound,
// overlaps with GEMM blocks on the same CUs — R11 measured this fusion at -22 us).
// Edges register-cached: each thread owns 16 edges (TK/256); src/dst read ONCE.
// Reservation: one returning atomicAdd on btot[g] per non-empty bucket
// (392 L2-resident counters — NOT R6's 1.6M-on-400KB failure mode).
// blocks >= nT: M=32 LSTM GEMM (M=64 cost +14 us in R10: VGPR/occupancy).
__global__ __launch_bounds__(256) void lstm_scatter_kernel(
    const float* __restrict__ x0, const float* __restrict__ x1,
    const unsigned short* __restrict__ wfrag,
    const float* __restrict__ b0, const float* __restrict__ b1,
    unsigned short* __restrict__ msg0, unsigned short* __restrict__ msg1,
    int N0, int N1, int nblk0,
    const int* __restrict__ src0, const int* __restrict__ dst0,
    const int* __restrict__ src1, const int* __restrict__ dst1,
    int* __restrict__ btot, unsigned* __restrict__ packed,
    int E0, int E1, int nbkt0, int NBKT, int nT)
{
    __shared__ unsigned short xs[32 * XPAD];
    __shared__ int h[MAXBKT];
    __shared__ int cur[MAXBKT];
    const int tid = threadIdx.x;

    if (blockIdx.x < nT) {   // ---- edge tile: hist + reserve + scatter, single edge read ----
        for (int i = tid; i < NBKT; i += 256) h[i] = 0;
        __syncthreads();
        const long long Etot = (long long)E0 + E1;
        const long long base = (long long)blockIdx.x * TK;
        int gg[16];
        unsigned pk[16];
#pragma unroll
        for (int j = 0; j < 16; j++) {
            long long e = base + j * 256 + tid;
            gg[j] = -1;
            if (e < Etot) {
                int s, d, g;
                if (e < E0) { d = dst0[e]; s = src0[e]; g = d >> 8; }
                else { long long ee = e - E0; d = dst1[ee]; s = src1[ee]; g = nbkt0 + (d >> 8); }
                gg[j] = g;
                pk[j] = ((unsigned)(d & 255) << 24) | (unsigned)s;
                atomicAdd(&h[g], 1);
            }
        }
        __syncthreads();
        for (int i = tid; i < NBKT; i += 256) {
            int c = h[i];
            cur[i] = i * SLOT + (c ? atomicAdd(&btot[i], c) : 0);
        }
        __syncthreads();
#pragma unroll
        for (int j = 0; j < 16; j++) {
            if (gg[j] >= 0) {
                int pos = atomicAdd(&cur[gg[j]], 1);
                packed[pos] = pk[j];
            }
        }
        return;
    }

    // ---- LSTM GEMM (M=32) ----
    const int lb = blockIdx.x - nT;
    const int rel = (lb >= nblk0);
    const int nb = (rel ? (lb - nblk0) : lb) * 32;
    const float* x = rel ? x1 : x0;
    const float* bias = rel ? b1 : b0;
    unsigned short* msg = rel ? msg1 : msg0;
    const int N = rel ? N1 : N0;
    const unsigned short* wf = wfrag + (size_t)rel * 6144 * 8;

    {
        int r = tid >> 3;
        int c0 = (tid & 7) * 16;
        int n = nb + r;
        unsigned short* dstp = xs + r * XPAD + c0;
        if (n < N) {
            const float4* srcp = (const float4*)(x + (size_t)n * CCH + c0);
#pragma unroll
            for (int qq = 0; qq < 4; qq++) {
                float4 v = srcp[qq];
                unsigned u0 = (unsigned)f2bf(v.x) | ((unsigned)f2bf(v.y) << 16);
                unsigned u1 = (unsigned)f2bf(v.z) | ((unsigned)f2bf(v.w) << 16);
                *(uint2*)(dstp + qq * 4) = make_uint2(u0, u1);
            }
        } else {
#pragma unroll
            for (int qq = 0; qq < 4; qq++) *(uint2*)(dstp + qq * 4) = make_uint2(0u, 0u);
        }
    }
    __syncthreads();

    const int w = tid >> 6;
    const int l = tid & 63;
    const int ctb2 = w * 2;             // 2 col-tiles per wave
    const int q = l >> 4;
    const int m16 = l & 15;

    floatx4 acc[3][2][2];               // [gate][ct][mt]
#pragma unroll
    for (int g = 0; g < 3; g++)
#pragma unroll
        for (int c = 0; c < 2; c++)
#pragma unroll
            for (int mt = 0; mt < 2; mt++) acc[g][c][mt] = (floatx4){0.f, 0.f, 0.f, 0.f};

    const unsigned short* arow0 = xs + m16 * XPAD + q * 8;
    const unsigned short* arow1 = xs + (16 + m16) * XPAD + q * 8;
#pragma unroll
    for (int kc = 0; kc < 4; kc++) {
        short8 af0 = *(const short8*)(arow0 + kc * 32);
        short8 af1 = *(const short8*)(arow1 + kc * 32);
#pragma unroll
        for (int g = 0; g < 3; g++)
#pragma unroll
            for (int c = 0; c < 2; c++) {
                const unsigned short* bp = wf + ((((size_t)g * 8 + (ctb2 + c)) * 4 + kc) * 64 + l) * 8;
                short8 bv = *(const short8*)bp;
                acc[g][c][0] = __builtin_amdgcn_mfma_f32_16x16x32_bf16(af0, bv, acc[g][c][0], 0, 0, 0);
                acc[g][c][1] = __builtin_amdgcn_mfma_f32_16x16x32_bf16(af1, bv, acc[g][c][1], 0, 0, 0);
            }
    }

    // epilogue: stage bf16 results in LDS (reuse xs), then write coalesced rows.
    __syncthreads();   // all waves done reading xs fragments
#pragma unroll
    for (int c = 0; c < 2; c++) {
        const int col = (ctb2 + c) * 16 + m16;
        const float bi = bias[col], bg = bias[256 + col], bo = bias[384 + col];
#pragma unroll
        for (int mt = 0; mt < 2; mt++)
#pragma unroll
            for (int r = 0; r < 4; r++) {
                const int nl = mt * 16 + q * 4 + r;
                float iv = sigmoidf_(acc[0][c][mt][r] + bi);
                float gv = tanh_fast(acc[1][c][mt][r] + bg);
                float ov = sigmoidf_(acc[2][c][mt][r] + bo);
                xs[nl * XPAD + col] = f2bf(ov * tanh_fast(iv * gv));
            }
    }
    __syncthreads();
    {
        int r = tid >> 3;
        int c0 = (tid & 7) * 16;        // 16 ushorts = 32 B per thread
        int n = nb + r;
        if (n < N) {
            const unsigned short* srow = xs + r * XPAD + c0;
            uint4 v0 = *(const uint4*)(srow);
            uint4 v1 = *(const uint4*)(srow + 8);
            unsigned short* drow = msg + (size_t)n * CCH + c0;
            *(uint4*)(drow) = v0;
            *(uint4*)(drow + 8) = v1;
        }
    }
}

// Pass 2: one block per bucket, 512 threads; in-LDS counting sort by 8-bit key.
// Direct final write (no sout staging / extra barrier / copy-back).
__global__ __launch_bounds__(512) void fine_sort_kernel(
    unsigned* __restrict__ packed, const int* __restrict__ btot,
    int* __restrict__ offs0, int* __restrict__ deg0,
    int* __restrict__ offs1, int* __restrict__ deg1,
    int N0, int N1, int nbkt0)
{
    __shared__ unsigned pin[FCAP];
    __shared__ int hist[256], scn[256], cur[256];
    const int g = blockIdx.x;
    const int tid = threadIdx.x;
    const int base = g * SLOT;
    const int cnt = min(btot[g], FCAP);

    for (int i = tid; i < cnt; i += 512) pin[i] = packed[base + i];
    if (tid < 256) hist[tid] = 0;
    __syncthreads();
    for (int i = tid; i < cnt; i += 512) atomicAdd(&hist[pin[i] >> 24], 1);
    __syncthreads();
    int v = (tid < 256) ? hist[tid] : 0;
    if (tid < 256) scn[tid] = v;
    __syncthreads();
    for (int off = 1; off < 256; off <<= 1) {
        int t = (tid >= off && tid < 256) ? scn[tid - off] : 0;
        __syncthreads();
        if (tid < 256) scn[tid] += t;
        __syncthreads();
    }
    if (tid < 256) {
        int excl = scn[tid] - v;
        cur[tid] = excl;
        const int rel = (g >= nbkt0);
        const int lb = rel ? g - nbkt0 : g;
        const int n = lb * 256 + tid;
        const int N = rel ? N1 : N0;
        if (n < N) {
            if (rel) { offs1[n] = base + excl; deg1[n] = v; }
            else     { offs0[n] = base + excl; deg0[n] = v; }
        }
    }
    __syncthreads();
    int* op = (int*)packed;
    for (int i = tid; i < cnt; i += 512) {
        unsigned p = pin[i];
        int pos = atomicAdd(&cur[p >> 24], 1);
        op[base + pos] = (int)(p & 0x00FFFFFFu);
    }
}

// ---------------- fused gather + linear + relu, SPLIT-NODE (M=16) ----------------
// 512 threads = 8 waves, 16 nodes/block (grid 2x). Each node is handled by TWO
// lane-groups: group A sums edges [0,cnt/2), group B sums [cnt/2,cnt) — per-group
// serial rounds drop 4 -> ~2 (deg~16, 4 edges/round). B writes f32 partials to
// LDS; A adds, converts to bf16, stores the MFMA operand. Same per-lane register
// footprint (VGPR ~32, R3 cliff respected); LDS 16.6 KB -> 4 blocks/CU unchanged.
// Rationale: R17 counters show 44% HBM / latency-chain-bound; halving the chain
// with constant occupancy should convert to throughput.
// Indices still software-pipelined (R14). NT x-loads + NT out-stores (R8/R10).
__global__ __launch_bounds__(512) void gather_linear_kernel(
    const float* __restrict__ xd0, const float* __restrict__ xd1,
    const unsigned short* __restrict__ msg0, const unsigned short* __restrict__ msg1,
    const int* __restrict__ csr,
    const int* __restrict__ offs0, const int* __restrict__ offs1,
    const int* __restrict__ deg0, const int* __restrict__ deg1,
    const unsigned short* __restrict__ wfrag,
    const float* __restrict__ bl0, const float* __restrict__ bl1,
    float* __restrict__ out0, float* __restrict__ out1,
    int P0, int P1, int N0, int N1)
{
    __shared__ unsigned short s[16 * APAD];
    __shared__ float part[16 * 128];
    const int tid = threadIdx.x;
    const int grp = blockIdx.x >> 3;
    const int sub = blockIdx.x & 7;
    const int rel = (sub >> 2) & 1;
    const int lb = grp * 4 + (sub & 3);
    const int P = rel ? P1 : P0;
    if (lb >= P) return;
    const int nb = lb * 16;
    const float* xd = rel ? xd1 : xd0;
    const unsigned short* msg = rel ? msg1 : msg0;
    const int* offs = rel ? offs1 : offs0;
    const int* deg = rel ? deg1 : deg0;
    const float* bl = rel ? bl1 : bl0;
    float* outp = rel ? out1 : out0;
    const int N = rel ? N1 : N0;
    const unsigned short* wf = wfrag + (size_t)rel * 4096 * 8;

    {   // stage x_dst (bf16) : 512 threads, 32/row, 4 floats each (NT load)
        int r = tid >> 5;
        int c0 = (tid & 31) * 4;
        int n = nb + r;
        unsigned short* drow = s + r * APAD + c0;
        if (n < N) {
            const floatx4* srcp = (const floatx4*)(xd + (size_t)n * CCH + c0);
            floatx4 v0 = __builtin_nontemporal_load(srcp);
            uint2 u;
            u.x = (unsigned)f2bf(v0[0]) | ((unsigned)f2bf(v0[1]) << 16);
            u.y = (unsigned)f2bf(v0[2]) | ((unsigned)f2bf(v0[3]) << 16);
            *(uint2*)drow = u;
        } else {
            *(uint2*)drow = make_uint2(0u, 0u);
        }
    }
    {   // gather: 2 lane-groups per node; pipelined indices
        const int w = tid >> 6;
        const int l = tid & 63;
        const int gidx = w * 4 + (l >> 4);  // 0..31
        const int nloc = gidx >> 1;         // node 0..15
        const int half = gidx & 1;
        const int c = l & 15;               // channels 8c..8c+7
        const int n = nb + nloc;
        float a0 = 0.f, a1 = 0.f, a2 = 0.f, a3 = 0.f;
        float a4 = 0.f, a5 = 0.f, a6 = 0.f, a7 = 0.f;
        if (n < N) {
            const int start = offs[n];
            const int cnt = deg[n];
            const int hh = cnt >> 1;
            const int* ce = csr + start + (half ? hh : 0);
            const int myCnt = half ? (cnt - hh) : hh;
            const unsigned short* mb = msg + c * 8;
#define ACC8(U) { \
            a0 += bf2f((unsigned short)(U.x)); a1 += bf2f((unsigned short)((U.x) >> 16)); \
            a2 += bf2f((unsigned short)(U.y)); a3 += bf2f((unsigned short)((U.y) >> 16)); \
            a4 += bf2f((unsigned short)(U.z)); a5 += bf2f((unsigned short)((U.z) >> 16)); \
            a6 += bf2f((unsigned short)(U.w)); a7 += bf2f((unsigned short)((U.w) >> 16)); }
            int j = 0;
            if (myCnt >= 4) {
                int s0 = ce[0], s1 = ce[1], s2 = ce[2], s3 = ce[3];
                for (; j + 8 <= myCnt; j += 4) {
                    uint4 u0 = *(const uint4*)(mb + (size_t)s0 * CCH);
                    uint4 u1 = *(const uint4*)(mb + (size_t)s1 * CCH);
                    uint4 u2 = *(const uint4*)(mb + (size_t)s2 * CCH);
                    uint4 u3 = *(const uint4*)(mb + (size_t)s3 * CCH);
                    s0 = ce[j + 4]; s1 = ce[j + 5]; s2 = ce[j + 6]; s3 = ce[j + 7];
                    ACC8(u0); ACC8(u1); ACC8(u2); ACC8(u3);
                }
                uint4 u0 = *(const uint4*)(mb + (size_t)s0 * CCH);
                uint4 u1 = *(const uint4*)(mb + (size_t)s1 * CCH);
                uint4 u2 = *(const uint4*)(mb + (size_t)s2 * CCH);
                uint4 u3 = *(const uint4*)(mb + (size_t)s3 * CCH);
                ACC8(u0); ACC8(u1); ACC8(u2); ACC8(u3);
                j += 4;
            }
            for (; j < myCnt; j++) {
                uint4 u0 = *(const uint4*)(mb + (size_t)ce[j] * CCH);
                ACC8(u0);
            }
#undef ACC8
        }
        if (half) {   // B: write f32 partials to LDS
            float* pp = part + nloc * 128 + c * 8;
            *(floatx4*)pp = (floatx4){a0, a1, a2, a3};
            *(floatx4*)(pp + 4) = (floatx4){a4, a5, a6, a7};
        }
        __syncthreads();
        if (!half) {  // A: add partials, convert, store MFMA operand
            const float* pp = part + nloc * 128 + c * 8;
            floatx4 p0 = *(const floatx4*)pp;
            floatx4 p1 = *(const floatx4*)(pp + 4);
            a0 += p0[0]; a1 += p0[1]; a2 += p0[2]; a3 += p0[3];
            a4 += p1[0]; a5 += p1[1]; a6 += p1[2]; a7 += p1[3];
            uint4 o;
            o.x = (unsigned)f2bf(a0) | ((unsigned)f2bf(a1) << 16);
            o.y = (unsigned)f2bf(a2) | ((unsigned)f2bf(a3) << 16);
            o.z = (unsigned)f2bf(a4) | ((unsigned)f2bf(a5) << 16);
            o.w = (unsigned)f2bf(a6) | ((unsigned)f2bf(a7) << 16);
            *(uint4*)(s + nloc * APAD + CCH + c * 8) = o;
        }
    }
    __syncthreads();

    // MFMA: wave w = col-tile w; single m-tile (16 nodes)
    const int w = tid >> 6;
    const int l = tid & 63;
    const int q = l >> 4;
    const int m16 = l & 15;

    floatx4 acc = (floatx4){0.f, 0.f, 0.f, 0.f};
    const unsigned short* arow0 = s + m16 * APAD + q * 8;
#pragma unroll
    for (int kc = 0; kc < 8; kc++) {
        short8 af0 = *(const short8*)(arow0 + kc * 32);
        const unsigned short* bp = wf + ((((size_t)w) * 8 + kc) * 64 + l) * 8;
        short8 bv = *(const short8*)bp;
        acc = __builtin_amdgcn_mfma_f32_16x16x32_bf16(af0, bv, acc, 0, 0, 0);
    }

    const int col = w * 16 + m16;
    const float bv = bl[col];
#pragma unroll
    for (int r = 0; r < 4; r++) {
        const int node = nb + q * 4 + r;
        if (node < N) {
            float v = fmaxf(acc[r] + bv, 0.0f);
            __builtin_nontemporal_store(v, &outp[(size_t)node * CCH + col]);
        }
    }
}

extern "C" void kernel_launch(void* const* d_in, const int* in_sizes, int n_in,
                              void* d_out, int out_size, void* d_ws, size_t ws_size,
                              hipStream_t stream) {
    const float* x_a      = (const float*)d_in[0];
    const float* x_b      = (const float*)d_in[1];
    const int*   e_ab     = (const int*)d_in[2];
    const int*   e_ba     = (const int*)d_in[3];
    const float* W_ih_ab  = (const float*)d_in[4];
    const float* b_ab     = (const float*)d_in[5];
    const float* W_lin_ab = (const float*)d_in[6];
    const float* b_lin_ab = (const float*)d_in[7];
    const float* W_ih_ba  = (const float*)d_in[8];
    const float* b_ba     = (const float*)d_in[9];
    const float* W_lin_ba = (const float*)d_in[10];
    const float* b_lin_ba = (const float*)d_in[11];

    const int NA = in_sizes[0] / CCH;
    const int NB = in_sizes[1] / CCH;
    const int E0 = in_sizes[2] / 2;   // a->b (dst in B)
    const int E1 = in_sizes[3] / 2;   // b->a (dst in A)

    float* out = (float*)d_out;
    char* ws = (char*)d_ws;
    size_t off = 0;
    auto alloc = [&](size_t bytes) { char* p = ws + off; off += (bytes + 255) & ~(size_t)255; return p; };

    unsigned short* wfrag_ih  = (unsigned short*)alloc(12288 * 8 * 2);
    unsigned short* wfrag_lin = (unsigned short*)alloc(8192 * 8 * 2);
    unsigned short* msg_a     = (unsigned short*)alloc((size_t)NA * CCH * 2);
    unsigned short* msg_b     = (unsigned short*)alloc((size_t)NB * CCH * 2);

    const int nbkt0 = (NB + 255) / 256;   // rel0 coarse buckets (dst in B)
    const int nbkt1 = (NA + 255) / 256;   // rel1 (dst in A)
    const int NBKT = nbkt0 + nbkt1;
    const long long Etot = (long long)E0 + E1;
    const int nT = (int)((Etot + TK - 1) / TK);

    int* btot   = (int*)alloc((size_t)NBKT * 4);
    int* offs_b = (int*)alloc((size_t)NB * 4);
    int* offs_a = (int*)alloc((size_t)NA * 4);
    int* deg_b  = (int*)alloc((size_t)NB * 4);
    int* deg_a  = (int*)alloc((size_t)NA * 4);
    unsigned* packed = (unsigned*)alloc((size_t)NBKT * SLOT * 4);  // fixed slots; becomes csr

    const int nblkA = (NA + 31) / 32;
    const int nblkB = (NB + 31) / 32;
    const int nblkA16 = (NA + 15) / 16;
    const int nblkB16 = (NB + 15) / 16;

    prep_weights_kernel<<<82, 256, 0, stream>>>(
        W_ih_ab, W_ih_ba, W_lin_ab, W_lin_ba, wfrag_ih, wfrag_lin, btot, NBKT);

    // fused: blocks [0,nT) = hist+reserve+scatter edge tiles; rest = LSTM GEMM
    lstm_scatter_kernel<<<nT + nblkA + nblkB, 256, 0, stream>>>(
        x_a, x_b, wfrag_ih, b_ab, b_ba, msg_a, msg_b, NA, NB, nblkA,
        e_ab, e_ab + E0, e_ba, e_ba + E1, btot, packed, E0, E1, nbkt0, NBKT, nT);

    fine_sort_kernel<<<NBKT, 512, 0, stream>>>(
        packed, btot, offs_b, deg_b, offs_a, deg_a, NB, NA, nbkt0);

    // split-node gather + linear; rel0 -> out_b (index 1), rel1 -> out_a (index 0)
    const int Pmax = (nblkB16 > nblkA16) ? nblkB16 : nblkA16;
    const int G = ((Pmax + 3) / 4) * 8;
    gather_linear_kernel<<<G, 512, 0, stream>>>(
        x_b, x_a, msg_a, msg_b, (const int*)packed,
        offs_b, offs_a, deg_b, deg_a, wfrag_lin, b_lin_ab, b_lin_ba,
        out + (size_t)NA * CCH, out, nblkB16, nblkA16, NB, NA);
}

// Round 19
// 235.679 us; speedup vs baseline: 1.0429x; 1.0429x over previous
//
#include <hip/hip_runtime.h>
#include <cstdint>
#include <cstddef>

#define CCH 128
#define TK 4096      // edges per tile: nT=391 edge-tile blocks fused into lstm launch; 16 edges/thread
#define FCAP 5120    // fine-sort bucket capacity == fixed slot size (bucket ~4096+-64, 16-sigma headroom)
#define SLOT 5120    // fixed packed-array slot per coarse bucket
#define MAXBKT 512   // max coarse buckets (392 actual)
#define XPAD 136     // 128 + 8 bf16 pad
#define APAD 264     // 256 + 8 pad

typedef __attribute__((ext_vector_type(8))) short short8;
typedef __attribute__((ext_vector_type(4))) float floatx4;

__device__ __forceinline__ unsigned short f2bf(float f) {
    unsigned u = __builtin_bit_cast(unsigned, f);
    u += 0x7fffu + ((u >> 16) & 1u);   // RNE
    return (unsigned short)(u >> 16);
}
__device__ __forceinline__ float bf2f(unsigned short h) {
    unsigned u = ((unsigned)h) << 16;
    return __builtin_bit_cast(float, u);
}
__device__ __forceinline__ float sigmoidf_(float x) { return 1.0f / (1.0f + __expf(-x)); }
__device__ __forceinline__ float tanh_fast(float x) {
    x = fminf(fmaxf(x, -10.0f), 10.0f);
    float e = __expf(2.0f * x);
    return (e - 1.0f) / (e + 1.0f);
}

// ---------------- merged weight prep + btot zeroing ----------------
__global__ __launch_bounds__(256) void prep_weights_kernel(
    const float* __restrict__ Wih0, const float* __restrict__ Wih1,
    const float* __restrict__ Wlin0, const float* __restrict__ Wlin1,
    unsigned short* __restrict__ frag_ih, unsigned short* __restrict__ frag_lin,
    int* __restrict__ btot, int NBKT)
{
    int t = blockIdx.x * 256 + threadIdx.x;
    if (t < 12288) {
        int l  = t & 63;
        int kc = (t >> 6) & 3;
        int ct = (t >> 8) & 7;
        int g  = (t >> 11) % 3;
        int rel = t / 6144;
        int gb = (g == 0) ? 0 : (g == 1 ? 256 : 384);
        const float* W = rel ? Wih1 : Wih0;
        int n  = gb + ct * 16 + (l & 15);
        int kb = kc * 32 + (l >> 4) * 8;
        unsigned short* o = frag_ih + (size_t)t * 8;
#pragma unroll
        for (int j = 0; j < 8; j++) o[j] = f2bf(W[(size_t)n * CCH + kb + j]);
    } else if (t < 20480) {
        int t2 = t - 12288;
        int l  = t2 & 63;
        int kc = (t2 >> 6) & 7;
        int ct = (t2 >> 9) & 7;
        int rel = t2 >> 12;
        const float* W = rel ? Wlin1 : Wlin0;
        int n  = ct * 16 + (l & 15);
        int kb = kc * 32 + (l >> 4) * 8;
        unsigned short* o = frag_lin + (size_t)t2 * 8;
#pragma unroll
        for (int j = 0; j < 8; j++) o[j] = f2bf(W[(size_t)n * 256 + kb + j]);
    } else {
        int z = t - 20480;
        if (z < NBKT) btot[z] = 0;
    }
}

// ---------------- fused: LSTM GEMM (M=32) + full CSR scatter tiles ----------------
// blocks [0,nT): histogram + atomic range reservation + scatter (latency-bound,
// overlaps with GEMM blocks on the same CUs — R11 measured this fusion at -22 us).
// Edges register-cached: each thread owns 16 edges (TK/256); src/dst read ONCE.
// Reservation: one returning atomicAdd on btot[g] per non-empty bucket
// (392 L2-resident counters — NOT R6's 1.6M-on-400KB failure mode).
// blocks >= nT: M=32 LSTM GEMM (M=64 cost +14 us in R10: VGPR/occupancy).
// Workload law (R3/R16/R18): any change that couples previously-independent
// waves (regs, fused state, intra-phase barriers) loses to occupancy/TLP.
__global__ __launch_bounds__(256) void lstm_scatter_kernel(
    const float* __restrict__ x0, const float* __restrict__ x1,
    const unsigned short* __restrict__ wfrag,
    const float* __restrict__ b0, const float* __restrict__ b1,
    unsigned short* __restrict__ msg0, unsigned short* __restrict__ msg1,
    int N0, int N1, int nblk0,
    const int* __restrict__ src0, const int* __restrict__ dst0,
    const int* __restrict__ src1, const int* __restrict__ dst1,
    int* __restrict__ btot, unsigned* __restrict__ packed,
    int E0, int E1, int nbkt0, int NBKT, int nT)
{
    __shared__ unsigned short xs[32 * XPAD];
    __shared__ int h[MAXBKT];
    __shared__ int cur[MAXBKT];
    const int tid = threadIdx.x;

    if (blockIdx.x < nT) {   // ---- edge tile: hist + reserve + scatter, single edge read ----
        for (int i = tid; i < NBKT; i += 256) h[i] = 0;
        __syncthreads();
        const long long Etot = (long long)E0 + E1;
        const long long base = (long long)blockIdx.x * TK;
        int gg[16];
        unsigned pk[16];
#pragma unroll
        for (int j = 0; j < 16; j++) {
            long long e = base + j * 256 + tid;
            gg[j] = -1;
            if (e < Etot) {
                int s, d, g;
                if (e < E0) { d = dst0[e]; s = src0[e]; g = d >> 8; }
                else { long long ee = e - E0; d = dst1[ee]; s = src1[ee]; g = nbkt0 + (d >> 8); }
                gg[j] = g;
                pk[j] = ((unsigned)(d & 255) << 24) | (unsigned)s;
                atomicAdd(&h[g], 1);
            }
        }
        __syncthreads();
        for (int i = tid; i < NBKT; i += 256) {
            int c = h[i];
            cur[i] = i * SLOT + (c ? atomicAdd(&btot[i], c) : 0);
        }
        __syncthreads();
#pragma unroll
        for (int j = 0; j < 16; j++) {
            if (gg[j] >= 0) {
                int pos = atomicAdd(&cur[gg[j]], 1);
                packed[pos] = pk[j];
            }
        }
        return;
    }

    // ---- LSTM GEMM (M=32) ----
    const int lb = blockIdx.x - nT;
    const int rel = (lb >= nblk0);
    const int nb = (rel ? (lb - nblk0) : lb) * 32;
    const float* x = rel ? x1 : x0;
    const float* bias = rel ? b1 : b0;
    unsigned short* msg = rel ? msg1 : msg0;
    const int N = rel ? N1 : N0;
    const unsigned short* wf = wfrag + (size_t)rel * 6144 * 8;

    {
        int r = tid >> 3;
        int c0 = (tid & 7) * 16;
        int n = nb + r;
        unsigned short* dstp = xs + r * XPAD + c0;
        if (n < N) {
            const float4* srcp = (const float4*)(x + (size_t)n * CCH + c0);
#pragma unroll
            for (int qq = 0; qq < 4; qq++) {
                float4 v = srcp[qq];
                unsigned u0 = (unsigned)f2bf(v.x) | ((unsigned)f2bf(v.y) << 16);
                unsigned u1 = (unsigned)f2bf(v.z) | ((unsigned)f2bf(v.w) << 16);
                *(uint2*)(dstp + qq * 4) = make_uint2(u0, u1);
            }
        } else {
#pragma unroll
            for (int qq = 0; qq < 4; qq++) *(uint2*)(dstp + qq * 4) = make_uint2(0u, 0u);
        }
    }
    __syncthreads();

    const int w = tid >> 6;
    const int l = tid & 63;
    const int ctb2 = w * 2;             // 2 col-tiles per wave
    const int q = l >> 4;
    const int m16 = l & 15;

    floatx4 acc[3][2][2];               // [gate][ct][mt]
#pragma unroll
    for (int g = 0; g < 3; g++)
#pragma unroll
        for (int c = 0; c < 2; c++)
#pragma unroll
            for (int mt = 0; mt < 2; mt++) acc[g][c][mt] = (floatx4){0.f, 0.f, 0.f, 0.f};

    const unsigned short* arow0 = xs + m16 * XPAD + q * 8;
    const unsigned short* arow1 = xs + (16 + m16) * XPAD + q * 8;
#pragma unroll
    for (int kc = 0; kc < 4; kc++) {
        short8 af0 = *(const short8*)(arow0 + kc * 32);
        short8 af1 = *(const short8*)(arow1 + kc * 32);
#pragma unroll
        for (int g = 0; g < 3; g++)
#pragma unroll
            for (int c = 0; c < 2; c++) {
                const unsigned short* bp = wf + ((((size_t)g * 8 + (ctb2 + c)) * 4 + kc) * 64 + l) * 8;
                short8 bv = *(const short8*)bp;
                acc[g][c][0] = __builtin_amdgcn_mfma_f32_16x16x32_bf16(af0, bv, acc[g][c][0], 0, 0, 0);
                acc[g][c][1] = __builtin_amdgcn_mfma_f32_16x16x32_bf16(af1, bv, acc[g][c][1], 0, 0, 0);
            }
    }

    // epilogue: stage bf16 results in LDS (reuse xs), then write coalesced rows.
    __syncthreads();   // all waves done reading xs fragments
#pragma unroll
    for (int c = 0; c < 2; c++) {
        const int col = (ctb2 + c) * 16 + m16;
        const float bi = bias[col], bg = bias[256 + col], bo = bias[384 + col];
#pragma unroll
        for (int mt = 0; mt < 2; mt++)
#pragma unroll
            for (int r = 0; r < 4; r++) {
                const int nl = mt * 16 + q * 4 + r;
                float iv = sigmoidf_(acc[0][c][mt][r] + bi);
                float gv = tanh_fast(acc[1][c][mt][r] + bg);
                float ov = sigmoidf_(acc[2][c][mt][r] + bo);
                xs[nl * XPAD + col] = f2bf(ov * tanh_fast(iv * gv));
            }
    }
    __syncthreads();
    {
        int r = tid >> 3;
        int c0 = (tid & 7) * 16;        // 16 ushorts = 32 B per thread
        int n = nb + r;
        if (n < N) {
            const unsigned short* srow = xs + r * XPAD + c0;
            uint4 v0 = *(const uint4*)(srow);
            uint4 v1 = *(const uint4*)(srow + 8);
            unsigned short* drow = msg + (size_t)n * CCH + c0;
            *(uint4*)(drow) = v0;
            *(uint4*)(drow + 8) = v1;
        }
    }
}

// Pass 2: one block per bucket, 512 threads; in-LDS counting sort by 8-bit key.
// Direct final write (no sout staging / extra barrier / copy-back).
__global__ __launch_bounds__(512) void fine_sort_kernel(
    unsigned* __restrict__ packed, const int* __restrict__ btot,
    int* __restrict__ offs0, int* __restrict__ deg0,
    int* __restrict__ offs1, int* __restrict__ deg1,
    int N0, int N1, int nbkt0)
{
    __shared__ unsigned pin[FCAP];
    __shared__ int hist[256], scn[256], cur[256];
    const int g = blockIdx.x;
    const int tid = threadIdx.x;
    const int base = g * SLOT;
    const int cnt = min(btot[g], FCAP);

    for (int i = tid; i < cnt; i += 512) pin[i] = packed[base + i];
    if (tid < 256) hist[tid] = 0;
    __syncthreads();
    for (int i = tid; i < cnt; i += 512) atomicAdd(&hist[pin[i] >> 24], 1);
    __syncthreads();
    int v = (tid < 256) ? hist[tid] : 0;
    if (tid < 256) scn[tid] = v;
    __syncthreads();
    for (int off = 1; off < 256; off <<= 1) {
        int t = (tid >= off && tid < 256) ? scn[tid - off] : 0;
        __syncthreads();
        if (tid < 256) scn[tid] += t;
        __syncthreads();
    }
    if (tid < 256) {
        int excl = scn[tid] - v;
        cur[tid] = excl;
        const int rel = (g >= nbkt0);
        const int lb = rel ? g - nbkt0 : g;
        const int n = lb * 256 + tid;
        const int N = rel ? N1 : N0;
        if (n < N) {
            if (rel) { offs1[n] = base + excl; deg1[n] = v; }
            else     { offs0[n] = base + excl; deg0[n] = v; }
        }
    }
    __syncthreads();
    int* op = (int*)packed;
    for (int i = tid; i < cnt; i += 512) {
        unsigned p = pin[i];
        int pos = atomicAdd(&cur[p >> 24], 1);
        op[base + pos] = (int)(p & 0x00FFFFFFu);
    }
}

// ---------------- fused gather + linear + relu ----------------
// 512 threads = 8 waves. XCD-split: (blockIdx&7)<4 -> rel0, else rel1.
// Gather: wave w, lane-group g=l>>4 owns node 4w+g; lane c=l&15 loads 16 B.
// Unroll kept at 4 (R3: unroll-8 = VGPR 44, occ 38%, dur 83 us. worse).
// Indices software-pipelined one round ahead (R14: gather 72->66 us).
// Split-node (2 groups/node, R18) rejected: intra-phase barrier couples waves,
// occ 72->58%, gather 66->78 us. Row-pipelining rejected (R3 VGPR cliff).
// x reads AND out writes NONTEMPORAL (R8/R9/R10 A/B: NT store -> gather
// 70 vs 74 us, FETCH 173 vs 178 MB).
__global__ __launch_bounds__(512) void gather_linear_kernel(
    const float* __restrict__ xd0, const float* __restrict__ xd1,
    const unsigned short* __restrict__ msg0, const unsigned short* __restrict__ msg1,
    const int* __restrict__ csr,
    const int* __restrict__ offs0, const int* __restrict__ offs1,
    const int* __restrict__ deg0, const int* __restrict__ deg1,
    const unsigned short* __restrict__ wfrag,
    const float* __restrict__ bl0, const float* __restrict__ bl1,
    float* __restrict__ out0, float* __restrict__ out1,
    int P0, int P1, int N0, int N1)
{
    __shared__ unsigned short s[32 * APAD];
    const int tid = threadIdx.x;
    const int grp = blockIdx.x >> 3;
    const int sub = blockIdx.x & 7;
    const int rel = (sub >> 2) & 1;
    const int lb = grp * 4 + (sub & 3);
    const int P = rel ? P1 : P0;
    if (lb >= P) return;
    const int nb = lb * 32;
    const float* xd = rel ? xd1 : xd0;
    const unsigned short* msg = rel ? msg1 : msg0;
    const int* offs = rel ? offs1 : offs0;
    const int* deg = rel ? deg1 : deg0;
    const float* bl = rel ? bl1 : bl0;
    float* outp = rel ? out1 : out0;
    const int N = rel ? N1 : N0;
    const unsigned short* wf = wfrag + (size_t)rel * 4096 * 8;

    {   // stage x_dst (bf16) : 512 threads, 16/row, 8 floats each (nontemporal load)
        int r = tid >> 4;
        int c0 = (tid & 15) * 8;
        int n = nb + r;
        unsigned short* drow = s + r * APAD + c0;
        if (n < N) {
            const floatx4* srcp = (const floatx4*)(xd + (size_t)n * CCH + c0);
            floatx4 v0 = __builtin_nontemporal_load(srcp);
            floatx4 v1 = __builtin_nontemporal_load(srcp + 1);
            uint4 u;
            u.x = (unsigned)f2bf(v0[0]) | ((unsigned)f2bf(v0[1]) << 16);
            u.y = (unsigned)f2bf(v0[2]) | ((unsigned)f2bf(v0[3]) << 16);
            u.z = (unsigned)f2bf(v1[0]) | ((unsigned)f2bf(v1[1]) << 16);
            u.w = (unsigned)f2bf(v1[2]) | ((unsigned)f2bf(v1[3]) << 16);
            *(uint4*)drow = u;
        } else {
            *(uint4*)drow = make_uint4(0u, 0u, 0u, 0u);
        }
    }
    {   // gather: lane-group per node, 16 B/lane, pipelined indices
        const int w = tid >> 6;
        const int l = tid & 63;
        const int g = l >> 4;           // lane group -> node 4w+g
        const int c = l & 15;           // channels 8c..8c+7
        const int nloc = w * 4 + g;
        const int n = nb + nloc;
        float a0 = 0.f, a1 = 0.f, a2 = 0.f, a3 = 0.f;
        float a4 = 0.f, a5 = 0.f, a6 = 0.f, a7 = 0.f;
        if (n < N) {
            const int start = offs[n];
            const int cnt = deg[n];
            const int* ce = csr + start;
            const unsigned short* mb = msg + c * 8;
#define ACC8(U) { \
            a0 += bf2f((unsigned short)(U.x)); a1 += bf2f((unsigned short)((U.x) >> 16)); \
            a2 += bf2f((unsigned short)(U.y)); a3 += bf2f((unsigned short)((U.y) >> 16)); \
            a4 += bf2f((unsigned short)(U.z)); a5 += bf2f((unsigned short)((U.z) >> 16)); \
            a6 += bf2f((unsigned short)(U.w)); a7 += bf2f((unsigned short)((U.w) >> 16)); }
            int j = 0;
            if (cnt >= 4) {
                int s0 = ce[0], s1 = ce[1], s2 = ce[2], s3 = ce[3];
                for (; j + 8 <= cnt; j += 4) {
                    uint4 u0 = *(const uint4*)(mb + (size_t)s0 * CCH);
                    uint4 u1 = *(const uint4*)(mb + (size_t)s1 * CCH);
                    uint4 u2 = *(const uint4*)(mb + (size_t)s2 * CCH);
                    uint4 u3 = *(const uint4*)(mb + (size_t)s3 * CCH);
                    s0 = ce[j + 4]; s1 = ce[j + 5]; s2 = ce[j + 6]; s3 = ce[j + 7];
                    ACC8(u0); ACC8(u1); ACC8(u2); ACC8(u3);
                }
                uint4 u0 = *(const uint4*)(mb + (size_t)s0 * CCH);
                uint4 u1 = *(const uint4*)(mb + (size_t)s1 * CCH);
                uint4 u2 = *(const uint4*)(mb + (size_t)s2 * CCH);
                uint4 u3 = *(const uint4*)(mb + (size_t)s3 * CCH);
                ACC8(u0); ACC8(u1); ACC8(u2); ACC8(u3);
                j += 4;
            }
            for (; j < cnt; j++) {
                uint4 u0 = *(const uint4*)(mb + (size_t)ce[j] * CCH);
                ACC8(u0);
            }
#undef ACC8
        }
        uint4 o;
        o.x = (unsigned)f2bf(a0) | ((unsigned)f2bf(a1) << 16);
        o.y = (unsigned)f2bf(a2) | ((unsigned)f2bf(a3) << 16);
        o.z = (unsigned)f2bf(a4) | ((unsigned)f2bf(a5) << 16);
        o.w = (unsigned)f2bf(a6) | ((unsigned)f2bf(a7) << 16);
        *(uint4*)(s + nloc * APAD + CCH + c * 8) = o;
    }
    __syncthreads();

    // MFMA: wave w = col-tile w; both m-tiles
    const int w = tid >> 6;
    const int l = tid & 63;
    const int q = l >> 4;
    const int m16 = l & 15;

    floatx4 acc[2];
    acc[0] = (floatx4){0.f, 0.f, 0.f, 0.f};
    acc[1] = (floatx4){0.f, 0.f, 0.f, 0.f};

    const unsigned short* arow0 = s + m16 * APAD + q * 8;
    const unsigned short* arow1 = s + (16 + m16) * APAD + q * 8;
#pragma unroll
    for (int kc = 0; kc < 8; kc++) {
        short8 af0 = *(const short8*)(arow0 + kc * 32);
        short8 af1 = *(const short8*)(arow1 + kc * 32);
        const unsigned short* bp = wf + ((((size_t)w) * 8 + kc) * 64 + l) * 8;
        short8 bv = *(const short8*)bp;
        acc[0] = __builtin_amdgcn_mfma_f32_16x16x32_bf16(af0, bv, acc[0], 0, 0, 0);
        acc[1] = __builtin_amdgcn_mfma_f32_16x16x32_bf16(af1, bv, acc[1], 0, 0, 0);
    }

    const int col = w * 16 + m16;
    const float bv = bl[col];
#pragma unroll
    for (int mt = 0; mt < 2; mt++)
#pragma unroll
        for (int r = 0; r < 4; r++) {
            const int node = nb + mt * 16 + q * 4 + r;
            if (node < N) {
                float v = fmaxf(acc[mt][r] + bv, 0.0f);
                __builtin_nontemporal_store(v, &outp[(size_t)node * CCH + col]);
            }
        }
}

extern "C" void kernel_launch(void* const* d_in, const int* in_sizes, int n_in,
                              void* d_out, int out_size, void* d_ws, size_t ws_size,
                              hipStream_t stream) {
    const float* x_a      = (const float*)d_in[0];
    const float* x_b      = (const float*)d_in[1];
    const int*   e_ab     = (const int*)d_in[2];
    const int*   e_ba     = (const int*)d_in[3];
    const float* W_ih_ab  = (const float*)d_in[4];
    const float* b_ab     = (const float*)d_in[5];
    const float* W_lin_ab = (const float*)d_in[6];
    const float* b_lin_ab = (const float*)d_in[7];
    const float* W_ih_ba  = (const float*)d_in[8];
    const float* b_ba     = (const float*)d_in[9];
    const float* W_lin_ba = (const float*)d_in[10];
    const float* b_lin_ba = (const float*)d_in[11];

    const int NA = in_sizes[0] / CCH;
    const int NB = in_sizes[1] / CCH;
    const int E0 = in_sizes[2] / 2;   // a->b (dst in B)
    const int E1 = in_sizes[3] / 2;   // b->a (dst in A)

    float* out = (float*)d_out;
    char* ws = (char*)d_ws;
    size_t off = 0;
    auto alloc = [&](size_t bytes) { char* p = ws + off; off += (bytes + 255) & ~(size_t)255; return p; };

    unsigned short* wfrag_ih  = (unsigned short*)alloc(12288 * 8 * 2);
    unsigned short* wfrag_lin = (unsigned short*)alloc(8192 * 8 * 2);
    unsigned short* msg_a     = (unsigned short*)alloc((size_t)NA * CCH * 2);
    unsigned short* msg_b     = (unsigned short*)alloc((size_t)NB * CCH * 2);

    const int nbkt0 = (NB + 255) / 256;   // rel0 coarse buckets (dst in B)
    const int nbkt1 = (NA + 255) / 256;   // rel1 (dst in A)
    const int NBKT = nbkt0 + nbkt1;
    const long long Etot = (long long)E0 + E1;
    const int nT = (int)((Etot + TK - 1) / TK);

    int* btot   = (int*)alloc((size_t)NBKT * 4);
    int* offs_b = (int*)alloc((size_t)NB * 4);
    int* offs_a = (int*)alloc((size_t)NA * 4);
    int* deg_b  = (int*)alloc((size_t)NB * 4);
    int* deg_a  = (int*)alloc((size_t)NA * 4);
    unsigned* packed = (unsigned*)alloc((size_t)NBKT * SLOT * 4);  // fixed slots; becomes csr

    const int nblkA = (NA + 31) / 32;
    const int nblkB = (NB + 31) / 32;

    prep_weights_kernel<<<82, 256, 0, stream>>>(
        W_ih_ab, W_ih_ba, W_lin_ab, W_lin_ba, wfrag_ih, wfrag_lin, btot, NBKT);

    // fused: blocks [0,nT) = hist+reserve+scatter edge tiles; rest = LSTM GEMM
    lstm_scatter_kernel<<<nT + nblkA + nblkB, 256, 0, stream>>>(
        x_a, x_b, wfrag_ih, b_ab, b_ba, msg_a, msg_b, NA, NB, nblkA,
        e_ab, e_ab + E0, e_ba, e_ba + E1, btot, packed, E0, E1, nbkt0, NBKT, nT);

    fine_sort_kernel<<<NBKT, 512, 0, stream>>>(
        packed, btot, offs_b, deg_b, offs_a, deg_a, NB, NA, nbkt0);

    // fused gather + linear; rel0 -> out_b (index 1), rel1 -> out_a (index 0)
    const int Pmax = (nblkB > nblkA) ? nblkB : nblkA;
    const int G = ((Pmax + 3) / 4) * 8;
    gather_linear_kernel<<<G, 512, 0, stream>>>(
        x_b, x_a, msg_a, msg_b, (const int*)packed,
        offs_b, offs_a, deg_b, deg_a, wfrag_lin, b_lin_ab, b_lin_ba,
        out + (size_t)NA * CCH, out, nblkB, nblkA, NB, NA);
}